// Round 2
// 952.119 us; speedup vs baseline: 1.0335x; 1.0335x over previous
//
#include <hip/hip_runtime.h>
#include <hip/hip_bf16.h>

#define N_A_NODES 100000
#define N_B_NODES 100000
#define D_FEAT    64
#define HIDDEN    128
#define NE        800000
#define CAP_MAX   48
#define NSLICE    100000   // column-major adjacency slice stride (= nodes/type)

// dst-windowed multi-pass adjacency build: keep the scatter window L2-resident
#define NPASS     8
#define PWIN      ((NSLICE + NPASS - 1) / NPASS)     // 12500 dst ids / pass
#define BPP       ((2 * NE + 255) / 256)             // 6250 blocks / pass

using bf16 = __hip_bfloat16;
typedef __bf16 bf16x8 __attribute__((ext_vector_type(8)));
typedef float  floatx4 __attribute__((ext_vector_type(4)));

// ---------------------------------------------------------------------------
// dtype-agnostic helpers (external tensors may be fp32 or bf16)
// ---------------------------------------------------------------------------
__device__ __forceinline__ __bf16 f2b(float x) {
    union { bf16 h; __bf16 b; } u;
    u.h = __float2bfloat16(x);
    return u.b;
}
__device__ __forceinline__ bf16x8 load8(const void* p, size_t off, bool f32) {
    if (f32) {
        const float* fp = (const float*)p + off;
        float4 a = *(const float4*)fp;
        float4 b = *(const float4*)(fp + 4);
        bf16x8 r;
        r[0] = f2b(a.x); r[1] = f2b(a.y); r[2] = f2b(a.z); r[3] = f2b(a.w);
        r[4] = f2b(b.x); r[5] = f2b(b.y); r[6] = f2b(b.z); r[7] = f2b(b.w);
        return r;
    }
    return *(const bf16x8*)((const bf16*)p + off);
}
__device__ __forceinline__ float loadf(const void* p, size_t off, bool f32) {
    return f32 ? ((const float*)p)[off]
               : __bfloat162float(((const bf16*)p)[off]);
}

// ---------------------------------------------------------------------------
// Runtime dtype detection, one wave.
// bit0: float tensors are fp32 ; bit1: node_id_A int64 ; bit2: edges int64
// ---------------------------------------------------------------------------
__global__ void detect(const unsigned int* __restrict__ xA_bits,
                       const unsigned int* __restrict__ idA_bits,
                       const unsigned int* __restrict__ eAB_bits,
                       int* __restrict__ flags)
{
    int lane = threadIdx.x;
    int inr = 0;
#pragma unroll
    for (int j = 0; j < 4; j++) {
        unsigned e = (xA_bits[lane * 4 + j] >> 7) & 0xFF;
        inr += (e >= 100 && e <= 135) ? 1 : 0;
    }
#pragma unroll
    for (int s = 32; s > 0; s >>= 1) inr += __shfl_down(inr, s);
    unsigned long long idnz = __ballot(idA_bits[2 * lane + 1] != 0);
    unsigned long long enz  = __ballot(eAB_bits[2 * lane + 1] != 0);
    if (lane == 0) {
        int f32  = (inr < 128) ? 1 : 0;
        int id64 = (idnz == 0) ? 1 : 0;
        int e64  = (enz == 0) ? 1 : 0;
        flags[0] = f32 | (id64 << 1) | (e64 << 2);
    }
}

// ---------------------------------------------------------------------------
// Convert all weight/bias params to bf16 once.
// ---------------------------------------------------------------------------
#define P_LINW  0
#define P_LINB  8192
#define P_WLAB  8320
#define P_BLAB  41088
#define P_WRAB  41344
#define P_WLBA  74112
#define P_BLBA  106880
#define P_WRBA  107136
#define P_TOTAL 139904

__global__ void convert_params(const void* __restrict__ linW, const void* __restrict__ linb,
                               const void* __restrict__ WlAB, const void* __restrict__ blAB,
                               const void* __restrict__ WrAB, const void* __restrict__ WlBA,
                               const void* __restrict__ blBA, const void* __restrict__ WrBA,
                               bf16* __restrict__ dst, const int* __restrict__ flags)
{
    bool f32 = flags[0] & 1;
    int t = blockIdx.x * blockDim.x + threadIdx.x;
    if (t >= P_TOTAL) return;
    const void* src; size_t off;
    if      (t < P_LINB) { src = linW; off = t - P_LINW; }
    else if (t < P_WLAB) { src = linb; off = t - P_LINB; }
    else if (t < P_BLAB) { src = WlAB; off = t - P_WLAB; }
    else if (t < P_WRAB) { src = blAB; off = t - P_BLAB; }
    else if (t < P_WLBA) { src = WrAB; off = t - P_WRAB; }
    else if (t < P_BLBA) { src = WlBA; off = t - P_WLBA; }
    else if (t < P_WRBA) { src = blBA; off = t - P_BLBA; }
    else                 { src = WrBA; off = t - P_WRBA; }
    dst[t] = __float2bfloat16(loadf(src, off, f32));
}

// ---------------------------------------------------------------------------
// Build COLUMN-MAJOR padded adjacency: adj[pos*NSLICE + dst] = src.
// dst-WINDOWED multi-pass scatter: pass p only inserts edges with
// dst in [p*PWIN, (p+1)*PWIN). Hot write window per pass ~1.4 MB
// (vs 12.8 MB single-pass) -> stays L2-resident, each 64-B adjacency
// line is filled while cached and evicted dirty ONCE instead of per-write.
// Blocks are pass-major so ~one pass is resident at a time.
// Edge lists are re-scanned NPASS times (L3-resident after pass 0).
// ---------------------------------------------------------------------------
__global__ void build_adj(const int* __restrict__ eAB, const int* __restrict__ eBA,
                          int* __restrict__ adjAB, int* __restrict__ cntB,
                          int* __restrict__ adjBA, int* __restrict__ cntA,
                          int cap, const int* __restrict__ flags)
{
    int st = (flags[0] & 4) ? 2 : 1;   // int64 edges: read low word (LE)
    int pass  = blockIdx.x / BPP;
    int chunk = blockIdx.x - pass * BPP;
    int lo = pass * PWIN;
    int hi = lo + PWIN;
    int e = chunk * blockDim.x + threadIdx.x;
    if (e < NE) {
        int dst = eAB[(size_t)(NE + e) * st];
        if (dst >= lo && dst < hi) {
            int src = eAB[(size_t)e * st];
            int pos = atomicAdd(&cntB[dst], 1);
            if (pos < cap) adjAB[(size_t)pos * NSLICE + dst] = src;
        }
    } else {
        int e2 = e - NE;
        if (e2 < NE) {
            int dst = eBA[(size_t)(NE + e2) * st];
            if (dst >= lo && dst < hi) {
                int src = eBA[(size_t)e2 * st];
                int pos = atomicAdd(&cntA[dst], 1);
                if (pos < cap) adjBA[(size_t)pos * NSLICE + dst] = src;
            }
        }
    }
}

// ---------------------------------------------------------------------------
// xA = x_A @ linA_W^T + linA_b + emb_A[idA]   (MFMA K=64; W/b pre-bf16)
// ---------------------------------------------------------------------------
__global__ __launch_bounds__(256) void fuse_input(
    const void* __restrict__ xin, const int* __restrict__ idA,
    const void* __restrict__ embA, const bf16* __restrict__ Wb,
    const bf16* __restrict__ bb, bf16* __restrict__ out,
    const int* __restrict__ flags)
{
    int fl = flags[0];
    bool f32 = fl & 1;
    int idst = (fl & 2) ? 2 : 1;
    int lane = threadIdx.x & 63;
    int wid  = threadIdx.x >> 6;
    int m0   = (blockIdx.x * 4 + wid) * 16;
    if (m0 >= N_A_NODES) return;
    int r = lane & 15, q = lane >> 4;

    floatx4 acc[8] = {};
#pragma unroll
    for (int s = 0; s < 2; s++) {
        bf16x8 a = load8(xin, (size_t)(m0 + r) * D_FEAT + s * 32 + q * 8, f32);
#pragma unroll
        for (int t = 0; t < 8; t++) {
            bf16x8 b = *(const bf16x8*)(Wb + (size_t)(t * 16 + r) * D_FEAT + s * 32 + q * 8);
            acc[t] = __builtin_amdgcn_mfma_f32_16x16x32_bf16(a, b, acc[t], 0, 0, 0);
        }
    }
#pragma unroll
    for (int t = 0; t < 8; t++) {
        int col = t * 16 + r;
        float bf = __bfloat162float(bb[col]);
#pragma unroll
        for (int rr = 0; rr < 4; rr++) {
            int row = m0 + q * 4 + rr;
            int id = idA[(size_t)row * idst];
            float v = acc[t][rr] + bf + loadf(embA, (size_t)id * HIDDEN + col, f32);
            out[(size_t)row * HIDDEN + col] = __float2bfloat16(v);
        }
    }
}

// ---------------------------------------------------------------------------
// xB = emb_B[idB]  (row gather, 4 elements/thread)
// ---------------------------------------------------------------------------
__global__ void copy_embB(const void* __restrict__ emb, const int* __restrict__ idB,
                          bf16* __restrict__ out, const int* __restrict__ flags)
{
    bool f32 = flags[0] & 1;
    int t = blockIdx.x * blockDim.x + threadIdx.x;
    int row = t >> 5;
    int g   = t & 31;
    if (row >= N_B_NODES) return;
    size_t s = (size_t)idB[row] * HIDDEN + g * 4;
    size_t d = (size_t)row * HIDDEN + g * 4;
    if (f32) {
        float4 v = *(const float4*)((const float*)emb + s);
        union { bf16 h[4]; uint2 u; } pk;
        pk.h[0] = __float2bfloat16(v.x); pk.h[1] = __float2bfloat16(v.y);
        pk.h[2] = __float2bfloat16(v.z); pk.h[3] = __float2bfloat16(v.w);
        *(uint2*)(out + d) = pk.u;
    } else {
        *(uint2*)(out + d) = *(const uint2*)((const bf16*)emb + s);
    }
}

// ---------------------------------------------------------------------------
// segment mean: one wave per dst node, fp32 accumulate; column-major adj.
// m_mode 0: store bf16 into ws buffer; m_mode 1: store external dtype @d_out.
// ---------------------------------------------------------------------------
__global__ __launch_bounds__(256) void aggregate(
    const bf16* __restrict__ feat, const int* __restrict__ adj,
    const int* __restrict__ cnt, void* __restrict__ outbase, size_t out_eoff,
    int m_mode, int Ndst, int cap, const int* __restrict__ flags)
{
    bool f32sel = m_mode ? (flags[0] & 1) : false;
    int wid  = (blockIdx.x * blockDim.x + threadIdx.x) >> 6;
    int lane = threadIdx.x & 63;
    if (wid >= Ndst) return;

    int c = cnt[wid];
    int n = c < cap ? c : cap;

    float a0 = 0.f, a1 = 0.f;
    for (int e = 0; e < n; e++) {
        int s = adj[(size_t)e * NSLICE + wid];
        const __hip_bfloat162* p = (const __hip_bfloat162*)(feat + (size_t)s * HIDDEN);
        float2 f = __bfloat1622float2(p[lane]);
        a0 += f.x;
        a1 += f.y;
    }
    float scale = 1.0f / (float)(c > 1 ? c : 1);
    a0 *= scale;
    a1 *= scale;
    size_t e0 = out_eoff + (size_t)wid * HIDDEN + 2 * lane;
    if (f32sel) {
        *(float2*)((float*)outbase + e0) = make_float2(a0, a1);
    } else {
        __hip_bfloat162 h;
        h.x = __float2bfloat16(a0);
        h.y = __float2bfloat16(a1);
        *(__hip_bfloat162*)((bf16*)outbase + e0) = h;
    }
}

// ---------------------------------------------------------------------------
// out = relu(A1 @ W1^T + bias + A2 @ W2^T)   (fused K=256 MFMA GEMM)
// A1: bf16 (a1_mode 0) or external dtype (a1_mode 1).  A2/W/b: bf16.
// out: internal bf16 (out_ext 0) or external dtype (out_ext 1).
// In-place safe (out aliasing A1/A2): each wave reads only rows it writes.
// ---------------------------------------------------------------------------
__global__ __launch_bounds__(256) void gemm_dual(
    const void* __restrict__ A1base, size_t a1_eoff, int a1_mode,
    const bf16* __restrict__ A2,
    const bf16* __restrict__ W1, const bf16* __restrict__ W2,
    const bf16* __restrict__ bias,
    void* __restrict__ outbase, size_t out_eoff, int out_ext,
    int N, const int* __restrict__ flags)
{
    bool extf32 = flags[0] & 1;
    bool a1f32  = a1_mode && extf32;
    bool outf   = out_ext && extf32;
    int lane = threadIdx.x & 63;
    int wid  = threadIdx.x >> 6;
    int m0   = (blockIdx.x * 4 + wid) * 16;
    if (m0 >= N) return;
    int r = lane & 15, q = lane >> 4;

    floatx4 acc[8] = {};
#pragma unroll
    for (int s = 0; s < 4; s++) {
        bf16x8 a = load8(A1base, a1_eoff + (size_t)(m0 + r) * HIDDEN + s * 32 + q * 8, a1f32);
#pragma unroll
        for (int t = 0; t < 8; t++) {
            bf16x8 b = *(const bf16x8*)(W1 + (size_t)(t * 16 + r) * HIDDEN + s * 32 + q * 8);
            acc[t] = __builtin_amdgcn_mfma_f32_16x16x32_bf16(a, b, acc[t], 0, 0, 0);
        }
    }
#pragma unroll
    for (int s = 0; s < 4; s++) {
        bf16x8 a = *(const bf16x8*)(A2 + (size_t)(m0 + r) * HIDDEN + s * 32 + q * 8);
#pragma unroll
        for (int t = 0; t < 8; t++) {
            bf16x8 b = *(const bf16x8*)(W2 + (size_t)(t * 16 + r) * HIDDEN + s * 32 + q * 8);
            acc[t] = __builtin_amdgcn_mfma_f32_16x16x32_bf16(a, b, acc[t], 0, 0, 0);
        }
    }
#pragma unroll
    for (int t = 0; t < 8; t++) {
        int col = t * 16 + r;
        float bf = __bfloat162float(bias[col]);
#pragma unroll
        for (int rr = 0; rr < 4; rr++) {
            float v = acc[t][rr] + bf;
            v = v > 0.f ? v : 0.f;
            size_t eo = out_eoff + (size_t)(m0 + q * 4 + rr) * HIDDEN + col;
            if (outf) ((float*)outbase)[eo] = v;
            else      ((bf16*)outbase)[eo] = __float2bfloat16(v);
        }
    }
}

// ---------------------------------------------------------------------------
extern "C" void kernel_launch(void* const* d_in, const int* in_sizes, int n_in,
                              void* d_out, int out_size, void* d_ws, size_t ws_size,
                              hipStream_t stream)
{
    const void* x_A  = d_in[0];
    const int*  idA  = (const int*)d_in[1];
    const int*  idB  = (const int*)d_in[2];
    const int*  eAB  = (const int*)d_in[3];
    const int*  eBA  = (const int*)d_in[4];
    const void* embA = d_in[5];
    const void* embB = d_in[6];

    // ---- workspace layout ----
    char* ws = (char*)d_ws;
    int*  cntB  = (int*)(ws + 0);           // 400000 B
    int*  cntA  = (int*)(ws + 400000);      // 400000 B
    int*  flags = (int*)(ws + 800000);      // 64 B
    bf16* pblk  = (bf16*)(ws + 800064);     // 279808 B of bf16 params
    const size_t XA_OFF = 1080000;
    const size_t XB_OFF = XA_OFF + 25600000;   // 26680000
    const size_t M_OFF  = XB_OFF + 25600000;   // 52280000
    bf16* xA = (bf16*)(ws + XA_OFF);
    bf16* xB = (bf16*)(ws + XB_OFF);

    // mAB/mBA: prefer bf16 in ws; fall back to external-dtype scratch in d_out
    // if ws is too small to also hold a decent adjacency.
    const size_t ADJ_M = M_OFF + 51200000;     // 103480000
    long long cap_m = ((long long)ws_size - (long long)ADJ_M) / 800000;
    int m_in_ws = (cap_m >= 16) ? 1 : 0;
    size_t adj_off = m_in_ws ? ADJ_M : M_OFF;
    long long capl = ((long long)ws_size - (long long)adj_off) / 800000;
    int cap = (int)capl;
    if (cap > CAP_MAX) cap = CAP_MAX;
    if (cap < 1) cap = 1;
    int* adjAB = (int*)(ws + adj_off);
    int* adjBA = (int*)(ws + adj_off + (size_t)cap * 400000);

    const size_t OUTB_EOFF = (size_t)N_A_NODES * HIDDEN;
    void*  mAB_base = m_in_ws ? (void*)(ws + M_OFF)            : d_out;
    void*  mBA_base = m_in_ws ? (void*)(ws + M_OFF + 25600000) : d_out;
    size_t mAB_eoff = m_in_ws ? 0 : OUTB_EOFF;
    size_t mBA_eoff = 0;
    int    m_mode   = m_in_ws ? 0 : 1;

    // bf16 param slices
    bf16* linWb = pblk + P_LINW;
    bf16* linbb = pblk + P_LINB;
    bf16* WlABb = pblk + P_WLAB;
    bf16* blABb = pblk + P_BLAB;
    bf16* WrABb = pblk + P_WRAB;
    bf16* WlBAb = pblk + P_WLBA;
    bf16* blBAb = pblk + P_BLBA;
    bf16* WrBAb = pblk + P_WRBA;

    (void)hipMemsetAsync(cntB, 0, 800000, stream);  // zeros cntB + cntA

    detect<<<1, 64, 0, stream>>>((const unsigned int*)x_A, (const unsigned int*)idA,
                                 (const unsigned int*)eAB, flags);
    convert_params<<<(P_TOTAL + 255) / 256, 256, 0, stream>>>(
        d_in[7], d_in[8], d_in[9], d_in[10], d_in[11], d_in[12], d_in[13], d_in[14],
        pblk, flags);
    build_adj<<<NPASS * BPP, 256, 0, stream>>>(eAB, eBA, adjAB, cntB,
                                               adjBA, cntA, cap, flags);
    fuse_input<<<(N_A_NODES + 63) / 64, 256, 0, stream>>>(x_A, idA, embA, linWb,
                                                          linbb, xA, flags);
    copy_embB<<<(N_B_NODES * 32 + 255) / 256, 256, 0, stream>>>(embB, idB, xB, flags);

    for (int l = 0; l < 2; l++) {
        bf16* wl_ab = WlABb + (size_t)l * HIDDEN * HIDDEN;
        bf16* wr_ab = WrABb + (size_t)l * HIDDEN * HIDDEN;
        bf16* wl_ba = WlBAb + (size_t)l * HIDDEN * HIDDEN;
        bf16* wr_ba = WrBAb + (size_t)l * HIDDEN * HIDDEN;
        bf16* b_ab  = blABb + (size_t)l * HIDDEN;
        bf16* b_ba  = blBAb + (size_t)l * HIDDEN;

        aggregate<<<(N_B_NODES + 3) / 4, 256, 0, stream>>>(
            xA, adjAB, cntB, mAB_base, mAB_eoff, m_mode, N_B_NODES, cap, flags);
        aggregate<<<(N_A_NODES + 3) / 4, 256, 0, stream>>>(
            xB, adjBA, cntA, mBA_base, mBA_eoff, m_mode, N_A_NODES, cap, flags);

        if (l == 0) {
            gemm_dual<<<(N_B_NODES + 63) / 64, 256, 0, stream>>>(
                mAB_base, mAB_eoff, m_mode, xB, wl_ab, wr_ab, b_ab,
                xB, 0, 0, N_B_NODES, flags);
            gemm_dual<<<(N_A_NODES + 63) / 64, 256, 0, stream>>>(
                mBA_base, mBA_eoff, m_mode, xA, wl_ba, wr_ba, b_ba,
                xA, 0, 0, N_A_NODES, flags);
        } else {
            gemm_dual<<<(N_B_NODES + 63) / 64, 256, 0, stream>>>(
                mAB_base, mAB_eoff, m_mode, xB, wl_ab, wr_ab, b_ab,
                d_out, OUTB_EOFF, 1, N_B_NODES, flags);
            gemm_dual<<<(N_A_NODES + 63) / 64, 256, 0, stream>>>(
                mBA_base, mBA_eoff, m_mode, xA, wl_ba, wr_ba, b_ba,
                d_out, 0, 1, N_A_NODES, flags);
        }
    }
}

// Round 3
// 778.031 us; speedup vs baseline: 1.2648x; 1.2238x over previous
//
#include <hip/hip_runtime.h>
#include <hip/hip_bf16.h>

#define N_A_NODES 100000
#define N_B_NODES 100000
#define D_FEAT    64
#define HIDDEN    128
#define NE        800000
#define CAP_MAX   48
#define NSLICE    100000   // column-major adjacency slice stride (= nodes/type)

// dst-windowed multi-pass adjacency build: keep the scatter window L2-resident
#define NPASS     8
#define PWIN      ((NSLICE + NPASS - 1) / NPASS)     // 12500 dst ids / pass
#define BPP       ((2 * NE + 255) / 256)             // 6250 blocks / pass

using bf16 = __hip_bfloat16;
typedef __bf16 bf16x8 __attribute__((ext_vector_type(8)));
typedef float  floatx4 __attribute__((ext_vector_type(4)));

// ---------------------------------------------------------------------------
// dtype-agnostic helpers (external tensors may be fp32 or bf16)
// ---------------------------------------------------------------------------
__device__ __forceinline__ __bf16 f2b(float x) {
    union { bf16 h; __bf16 b; } u;
    u.h = __float2bfloat16(x);
    return u.b;
}
__device__ __forceinline__ bf16x8 load8(const void* p, size_t off, bool f32) {
    if (f32) {
        const float* fp = (const float*)p + off;
        float4 a = *(const float4*)fp;
        float4 b = *(const float4*)(fp + 4);
        bf16x8 r;
        r[0] = f2b(a.x); r[1] = f2b(a.y); r[2] = f2b(a.z); r[3] = f2b(a.w);
        r[4] = f2b(b.x); r[5] = f2b(b.y); r[6] = f2b(b.z); r[7] = f2b(b.w);
        return r;
    }
    return *(const bf16x8*)((const bf16*)p + off);
}
__device__ __forceinline__ float loadf(const void* p, size_t off, bool f32) {
    return f32 ? ((const float*)p)[off]
               : __bfloat162float(((const bf16*)p)[off]);
}

// ---------------------------------------------------------------------------
// Runtime dtype detection, one wave.
// bit0: float tensors are fp32 ; bit1: node_id_A int64 ; bit2: edges int64
// ---------------------------------------------------------------------------
__global__ void detect(const unsigned int* __restrict__ xA_bits,
                       const unsigned int* __restrict__ idA_bits,
                       const unsigned int* __restrict__ eAB_bits,
                       int* __restrict__ flags)
{
    int lane = threadIdx.x;
    int inr = 0;
#pragma unroll
    for (int j = 0; j < 4; j++) {
        unsigned e = (xA_bits[lane * 4 + j] >> 7) & 0xFF;
        inr += (e >= 100 && e <= 135) ? 1 : 0;
    }
#pragma unroll
    for (int s = 32; s > 0; s >>= 1) inr += __shfl_down(inr, s);
    unsigned long long idnz = __ballot(idA_bits[2 * lane + 1] != 0);
    unsigned long long enz  = __ballot(eAB_bits[2 * lane + 1] != 0);
    if (lane == 0) {
        int f32  = (inr < 128) ? 1 : 0;
        int id64 = (idnz == 0) ? 1 : 0;
        int e64  = (enz == 0) ? 1 : 0;
        flags[0] = f32 | (id64 << 1) | (e64 << 2);
    }
}

// ---------------------------------------------------------------------------
// Convert all weight/bias params to bf16 once.
// ---------------------------------------------------------------------------
#define P_LINW  0
#define P_LINB  8192
#define P_WLAB  8320
#define P_BLAB  41088
#define P_WRAB  41344
#define P_WLBA  74112
#define P_BLBA  106880
#define P_WRBA  107136
#define P_TOTAL 139904

__global__ void convert_params(const void* __restrict__ linW, const void* __restrict__ linb,
                               const void* __restrict__ WlAB, const void* __restrict__ blAB,
                               const void* __restrict__ WrAB, const void* __restrict__ WlBA,
                               const void* __restrict__ blBA, const void* __restrict__ WrBA,
                               bf16* __restrict__ dst, const int* __restrict__ flags)
{
    bool f32 = flags[0] & 1;
    int t = blockIdx.x * blockDim.x + threadIdx.x;
    if (t >= P_TOTAL) return;
    const void* src; size_t off;
    if      (t < P_LINB) { src = linW; off = t - P_LINW; }
    else if (t < P_WLAB) { src = linb; off = t - P_LINB; }
    else if (t < P_BLAB) { src = WlAB; off = t - P_WLAB; }
    else if (t < P_WRAB) { src = blAB; off = t - P_BLAB; }
    else if (t < P_WLBA) { src = WrAB; off = t - P_WRAB; }
    else if (t < P_BLBA) { src = WlBA; off = t - P_WLBA; }
    else if (t < P_WRBA) { src = blBA; off = t - P_BLBA; }
    else                 { src = WrBA; off = t - P_WRBA; }
    dst[t] = __float2bfloat16(loadf(src, off, f32));
}

// ---------------------------------------------------------------------------
// Build COLUMN-MAJOR padded adjacency: adj[pos*NSLICE + dst] = src.
// dst-WINDOWED multi-pass scatter keeps the hot write window L2-resident
// (round-2 verified: build_adj dropped out of the top-5 dispatches).
// ---------------------------------------------------------------------------
__global__ void build_adj(const int* __restrict__ eAB, const int* __restrict__ eBA,
                          int* __restrict__ adjAB, int* __restrict__ cntB,
                          int* __restrict__ adjBA, int* __restrict__ cntA,
                          int cap, const int* __restrict__ flags)
{
    int st = (flags[0] & 4) ? 2 : 1;   // int64 edges: read low word (LE)
    int pass  = blockIdx.x / BPP;
    int chunk = blockIdx.x - pass * BPP;
    int lo = pass * PWIN;
    int hi = lo + PWIN;
    int e = chunk * blockDim.x + threadIdx.x;
    if (e < NE) {
        int dst = eAB[(size_t)(NE + e) * st];
        if (dst >= lo && dst < hi) {
            int src = eAB[(size_t)e * st];
            int pos = atomicAdd(&cntB[dst], 1);
            if (pos < cap) adjAB[(size_t)pos * NSLICE + dst] = src;
        }
    } else {
        int e2 = e - NE;
        if (e2 < NE) {
            int dst = eBA[(size_t)(NE + e2) * st];
            if (dst >= lo && dst < hi) {
                int src = eBA[(size_t)e2 * st];
                int pos = atomicAdd(&cntA[dst], 1);
                if (pos < cap) adjBA[(size_t)pos * NSLICE + dst] = src;
            }
        }
    }
}

// ---------------------------------------------------------------------------
// xA = x_A @ linA_W^T + linA_b + emb_A[idA]   (MFMA K=64; W/b pre-bf16)
// ---------------------------------------------------------------------------
__global__ __launch_bounds__(256) void fuse_input(
    const void* __restrict__ xin, const int* __restrict__ idA,
    const void* __restrict__ embA, const bf16* __restrict__ Wb,
    const bf16* __restrict__ bb, bf16* __restrict__ out,
    const int* __restrict__ flags)
{
    int fl = flags[0];
    bool f32 = fl & 1;
    int idst = (fl & 2) ? 2 : 1;
    int lane = threadIdx.x & 63;
    int wid  = threadIdx.x >> 6;
    int m0   = (blockIdx.x * 4 + wid) * 16;
    if (m0 >= N_A_NODES) return;
    int r = lane & 15, q = lane >> 4;

    floatx4 acc[8] = {};
#pragma unroll
    for (int s = 0; s < 2; s++) {
        bf16x8 a = load8(xin, (size_t)(m0 + r) * D_FEAT + s * 32 + q * 8, f32);
#pragma unroll
        for (int t = 0; t < 8; t++) {
            bf16x8 b = *(const bf16x8*)(Wb + (size_t)(t * 16 + r) * D_FEAT + s * 32 + q * 8);
            acc[t] = __builtin_amdgcn_mfma_f32_16x16x32_bf16(a, b, acc[t], 0, 0, 0);
        }
    }
#pragma unroll
    for (int t = 0; t < 8; t++) {
        int col = t * 16 + r;
        float bf = __bfloat162float(bb[col]);
#pragma unroll
        for (int rr = 0; rr < 4; rr++) {
            int row = m0 + q * 4 + rr;
            int id = idA[(size_t)row * idst];
            float v = acc[t][rr] + bf + loadf(embA, (size_t)id * HIDDEN + col, f32);
            out[(size_t)row * HIDDEN + col] = __float2bfloat16(v);
        }
    }
}

// ---------------------------------------------------------------------------
// xB = emb_B[idB]  (row gather, 4 elements/thread)
// ---------------------------------------------------------------------------
__global__ void copy_embB(const void* __restrict__ emb, const int* __restrict__ idB,
                          bf16* __restrict__ out, const int* __restrict__ flags)
{
    bool f32 = flags[0] & 1;
    int t = blockIdx.x * blockDim.x + threadIdx.x;
    int row = t >> 5;
    int g   = t & 31;
    if (row >= N_B_NODES) return;
    size_t s = (size_t)idB[row] * HIDDEN + g * 4;
    size_t d = (size_t)row * HIDDEN + g * 4;
    if (f32) {
        float4 v = *(const float4*)((const float*)emb + s);
        union { bf16 h[4]; uint2 u; } pk;
        pk.h[0] = __float2bfloat16(v.x); pk.h[1] = __float2bfloat16(v.y);
        pk.h[2] = __float2bfloat16(v.z); pk.h[3] = __float2bfloat16(v.w);
        *(uint2*)(out + d) = pk.u;
    } else {
        *(uint2*)(out + d) = *(const uint2*)((const bf16*)emb + s);
    }
}

// ---------------------------------------------------------------------------
// segment mean: one wave per dst node, fp32 accumulate; column-major adj.
// Quarter-wave gather: 16 lanes x bf16x8 (16 B) cover one 256-B feat row,
// so ONE vmem instruction gathers 4 edges; unroll x2 = 8 edges in flight
// (avg degree = 8). adj entries vector-loaded once (lane e holds entry e,
// cap<=48<64) and broadcast via shfl — removes the per-edge serial
// adj-load -> gather dependence chain that limited R2 to 1 outstanding
// gather per wave (93.6 us, 1.9 TB/s, latency-bound).
// m_mode 0: store bf16 into ws buffer; m_mode 1: store external dtype @d_out.
// ---------------------------------------------------------------------------
__device__ __forceinline__ void accum8(float* acc, bf16x8 v) {
    union { bf16x8 v8; __hip_bfloat162 h2[4]; } u;
    u.v8 = v;
#pragma unroll
    for (int j = 0; j < 4; j++) {
        float2 f = __bfloat1622float2(u.h2[j]);
        acc[2 * j]     += f.x;
        acc[2 * j + 1] += f.y;
    }
}

__global__ __launch_bounds__(256) void aggregate(
    const bf16* __restrict__ feat, const int* __restrict__ adj,
    const int* __restrict__ cnt, void* __restrict__ outbase, size_t out_eoff,
    int m_mode, int Ndst, int cap, const int* __restrict__ flags)
{
    bool f32sel = m_mode ? (flags[0] & 1) : false;
    int wid  = (blockIdx.x * blockDim.x + threadIdx.x) >> 6;
    int lane = threadIdx.x & 63;
    if (wid >= Ndst) return;

    int c = cnt[wid];
    int n = c < cap ? c : cap;

    // one coalesced vector load replaces n serial lane-uniform loads
    int myadj = (lane < n) ? adj[(size_t)lane * NSLICE + wid] : 0;

    int q  = lane >> 4;        // quarter-wave: which edge of the group of 4
    int cl = lane & 15;        // column block: 8 bf16 per lane

    float acc[8] = {};
    int e = 0;
    for (; e + 8 <= n; e += 8) {
        int s0 = __shfl(myadj, e + q);
        int s1 = __shfl(myadj, e + 4 + q);
        bf16x8 v0 = *(const bf16x8*)(feat + (size_t)s0 * HIDDEN + cl * 8);
        bf16x8 v1 = *(const bf16x8*)(feat + (size_t)s1 * HIDDEN + cl * 8);
        accum8(acc, v0);
        accum8(acc, v1);
    }
    for (; e < n; e += 4) {
        int idx = e + q;
        int s = __shfl(myadj, idx < n ? idx : 0);
        bf16x8 v = *(const bf16x8*)(feat + (size_t)s * HIDDEN + cl * 8);
        if (idx < n) accum8(acc, v);
    }

    // reduce across the 4 quarter-waves (same cl, different q)
#pragma unroll
    for (int j = 0; j < 8; j++) {
        acc[j] += __shfl_xor(acc[j], 16);
        acc[j] += __shfl_xor(acc[j], 32);
    }

    float scale = 1.0f / (float)(c > 1 ? c : 1);
    if (q == 0) {
        size_t rowbase = out_eoff + (size_t)wid * HIDDEN + cl * 8;
        if (f32sel) {
            float* op = (float*)outbase + rowbase;
            *(float4*)op       = make_float4(acc[0] * scale, acc[1] * scale,
                                             acc[2] * scale, acc[3] * scale);
            *(float4*)(op + 4) = make_float4(acc[4] * scale, acc[5] * scale,
                                             acc[6] * scale, acc[7] * scale);
        } else {
            union { bf16 h[8]; uint4 u; } pk;
#pragma unroll
            for (int j = 0; j < 8; j++) pk.h[j] = __float2bfloat16(acc[j] * scale);
            *(uint4*)((bf16*)outbase + rowbase) = pk.u;
        }
    }
}

// ---------------------------------------------------------------------------
// out = relu(A1 @ W1^T + bias + A2 @ W2^T)   (fused K=256 MFMA GEMM)
// A1: bf16 (a1_mode 0) or external dtype (a1_mode 1).  A2/W/b: bf16.
// out: internal bf16 (out_ext 0) or external dtype (out_ext 1).
// In-place safe (out aliasing A1/A2): each wave reads only rows it writes.
// ---------------------------------------------------------------------------
__global__ __launch_bounds__(256) void gemm_dual(
    const void* __restrict__ A1base, size_t a1_eoff, int a1_mode,
    const bf16* __restrict__ A2,
    const bf16* __restrict__ W1, const bf16* __restrict__ W2,
    const bf16* __restrict__ bias,
    void* __restrict__ outbase, size_t out_eoff, int out_ext,
    int N, const int* __restrict__ flags)
{
    bool extf32 = flags[0] & 1;
    bool a1f32  = a1_mode && extf32;
    bool outf   = out_ext && extf32;
    int lane = threadIdx.x & 63;
    int wid  = threadIdx.x >> 6;
    int m0   = (blockIdx.x * 4 + wid) * 16;
    if (m0 >= N) return;
    int r = lane & 15, q = lane >> 4;

    floatx4 acc[8] = {};
#pragma unroll
    for (int s = 0; s < 4; s++) {
        bf16x8 a = load8(A1base, a1_eoff + (size_t)(m0 + r) * HIDDEN + s * 32 + q * 8, a1f32);
#pragma unroll
        for (int t = 0; t < 8; t++) {
            bf16x8 b = *(const bf16x8*)(W1 + (size_t)(t * 16 + r) * HIDDEN + s * 32 + q * 8);
            acc[t] = __builtin_amdgcn_mfma_f32_16x16x32_bf16(a, b, acc[t], 0, 0, 0);
        }
    }
#pragma unroll
    for (int s = 0; s < 4; s++) {
        bf16x8 a = *(const bf16x8*)(A2 + (size_t)(m0 + r) * HIDDEN + s * 32 + q * 8);
#pragma unroll
        for (int t = 0; t < 8; t++) {
            bf16x8 b = *(const bf16x8*)(W2 + (size_t)(t * 16 + r) * HIDDEN + s * 32 + q * 8);
            acc[t] = __builtin_amdgcn_mfma_f32_16x16x32_bf16(a, b, acc[t], 0, 0, 0);
        }
    }
#pragma unroll
    for (int t = 0; t < 8; t++) {
        int col = t * 16 + r;
        float bf = __bfloat162float(bias[col]);
#pragma unroll
        for (int rr = 0; rr < 4; rr++) {
            float v = acc[t][rr] + bf;
            v = v > 0.f ? v : 0.f;
            size_t eo = out_eoff + (size_t)(m0 + q * 4 + rr) * HIDDEN + col;
            if (outf) ((float*)outbase)[eo] = v;
            else      ((bf16*)outbase)[eo] = __float2bfloat16(v);
        }
    }
}

// ---------------------------------------------------------------------------
extern "C" void kernel_launch(void* const* d_in, const int* in_sizes, int n_in,
                              void* d_out, int out_size, void* d_ws, size_t ws_size,
                              hipStream_t stream)
{
    const void* x_A  = d_in[0];
    const int*  idA  = (const int*)d_in[1];
    const int*  idB  = (const int*)d_in[2];
    const int*  eAB  = (const int*)d_in[3];
    const int*  eBA  = (const int*)d_in[4];
    const void* embA = d_in[5];
    const void* embB = d_in[6];

    // ---- workspace layout ----
    char* ws = (char*)d_ws;
    int*  cntB  = (int*)(ws + 0);           // 400000 B
    int*  cntA  = (int*)(ws + 400000);      // 400000 B
    int*  flags = (int*)(ws + 800000);      // 64 B
    bf16* pblk  = (bf16*)(ws + 800064);     // 279808 B of bf16 params
    const size_t XA_OFF = 1080000;
    const size_t XB_OFF = XA_OFF + 25600000;   // 26680000
    const size_t M_OFF  = XB_OFF + 25600000;   // 52280000
    bf16* xA = (bf16*)(ws + XA_OFF);
    bf16* xB = (bf16*)(ws + XB_OFF);

    // mAB/mBA: prefer bf16 in ws; fall back to external-dtype scratch in d_out
    // if ws is too small to also hold a decent adjacency.
    const size_t ADJ_M = M_OFF + 51200000;     // 103480000
    long long cap_m = ((long long)ws_size - (long long)ADJ_M) / 800000;
    int m_in_ws = (cap_m >= 16) ? 1 : 0;
    size_t adj_off = m_in_ws ? ADJ_M : M_OFF;
    long long capl = ((long long)ws_size - (long long)adj_off) / 800000;
    int cap = (int)capl;
    if (cap > CAP_MAX) cap = CAP_MAX;
    if (cap < 1) cap = 1;
    int* adjAB = (int*)(ws + adj_off);
    int* adjBA = (int*)(ws + adj_off + (size_t)cap * 400000);

    const size_t OUTB_EOFF = (size_t)N_A_NODES * HIDDEN;
    void*  mAB_base = m_in_ws ? (void*)(ws + M_OFF)            : d_out;
    void*  mBA_base = m_in_ws ? (void*)(ws + M_OFF + 25600000) : d_out;
    size_t mAB_eoff = m_in_ws ? 0 : OUTB_EOFF;
    size_t mBA_eoff = 0;
    int    m_mode   = m_in_ws ? 0 : 1;

    // bf16 param slices
    bf16* linWb = pblk + P_LINW;
    bf16* linbb = pblk + P_LINB;
    bf16* WlABb = pblk + P_WLAB;
    bf16* blABb = pblk + P_BLAB;
    bf16* WrABb = pblk + P_WRAB;
    bf16* WlBAb = pblk + P_WLBA;
    bf16* blBAb = pblk + P_BLBA;
    bf16* WrBAb = pblk + P_WRBA;

    (void)hipMemsetAsync(cntB, 0, 800000, stream);  // zeros cntB + cntA

    detect<<<1, 64, 0, stream>>>((const unsigned int*)x_A, (const unsigned int*)idA,
                                 (const unsigned int*)eAB, flags);
    convert_params<<<(P_TOTAL + 255) / 256, 256, 0, stream>>>(
        d_in[7], d_in[8], d_in[9], d_in[10], d_in[11], d_in[12], d_in[13], d_in[14],
        pblk, flags);
    build_adj<<<NPASS * BPP, 256, 0, stream>>>(eAB, eBA, adjAB, cntB,
                                               adjBA, cntA, cap, flags);
    fuse_input<<<(N_A_NODES + 63) / 64, 256, 0, stream>>>(x_A, idA, embA, linWb,
                                                          linbb, xA, flags);
    copy_embB<<<(N_B_NODES * 32 + 255) / 256, 256, 0, stream>>>(embB, idB, xB, flags);

    for (int l = 0; l < 2; l++) {
        bf16* wl_ab = WlABb + (size_t)l * HIDDEN * HIDDEN;
        bf16* wr_ab = WrABb + (size_t)l * HIDDEN * HIDDEN;
        bf16* wl_ba = WlBAb + (size_t)l * HIDDEN * HIDDEN;
        bf16* wr_ba = WrBAb + (size_t)l * HIDDEN * HIDDEN;
        bf16* b_ab  = blABb + (size_t)l * HIDDEN;
        bf16* b_ba  = blBAb + (size_t)l * HIDDEN;

        aggregate<<<(N_B_NODES + 3) / 4, 256, 0, stream>>>(
            xA, adjAB, cntB, mAB_base, mAB_eoff, m_mode, N_B_NODES, cap, flags);
        aggregate<<<(N_A_NODES + 3) / 4, 256, 0, stream>>>(
            xB, adjBA, cntA, mBA_base, mBA_eoff, m_mode, N_A_NODES, cap, flags);

        if (l == 0) {
            gemm_dual<<<(N_B_NODES + 63) / 64, 256, 0, stream>>>(
                mAB_base, mAB_eoff, m_mode, xB, wl_ab, wr_ab, b_ab,
                xB, 0, 0, N_B_NODES, flags);
            gemm_dual<<<(N_A_NODES + 63) / 64, 256, 0, stream>>>(
                mBA_base, mBA_eoff, m_mode, xA, wl_ba, wr_ba, b_ba,
                xA, 0, 0, N_A_NODES, flags);
        } else {
            gemm_dual<<<(N_B_NODES + 63) / 64, 256, 0, stream>>>(
                mAB_base, mAB_eoff, m_mode, xB, wl_ab, wr_ab, b_ab,
                d_out, OUTB_EOFF, 1, N_B_NODES, flags);
            gemm_dual<<<(N_A_NODES + 63) / 64, 256, 0, stream>>>(
                mBA_base, mBA_eoff, m_mode, xA, wl_ba, wr_ba, b_ba,
                d_out, 0, 1, N_A_NODES, flags);
        }
    }
}

// Round 12
// 773.309 us; speedup vs baseline: 1.2725x; 1.0061x over previous
//
#include <hip/hip_runtime.h>
#include <hip/hip_bf16.h>

#define N_A_NODES 100000
#define N_B_NODES 100000
#define D_FEAT    64
#define HIDDEN    128
#define NE        800000
#define CAP_MAX   48
#define NSLICE    100000   // column-major adjacency slice stride (= nodes/type)

// XCD-owned dst partitioning for the adjacency build:
// chunk c = blockIdx%8 (round-robin XCD proxy) owns dst in [c*PWIN,(c+1)*PWIN)
#define NXCD      8
#define PWIN      ((NSLICE + NXCD - 1) / NXCD)       // 12500 dst ids / XCD
#define BPP       ((2 * NE + 255) / 256)             // 6250 edge-chunks

using bf16 = __hip_bfloat16;
typedef __bf16 bf16x8 __attribute__((ext_vector_type(8)));
typedef float  floatx4 __attribute__((ext_vector_type(4)));

// ---------------------------------------------------------------------------
// dtype-agnostic helpers (external tensors may be fp32 or bf16)
// ---------------------------------------------------------------------------
__device__ __forceinline__ __bf16 f2b(float x) {
    union { bf16 h; __bf16 b; } u;
    u.h = __float2bfloat16(x);
    return u.b;
}
__device__ __forceinline__ bf16x8 load8(const void* p, size_t off, bool f32) {
    if (f32) {
        const float* fp = (const float*)p + off;
        float4 a = *(const float4*)fp;
        float4 b = *(const float4*)(fp + 4);
        bf16x8 r;
        r[0] = f2b(a.x); r[1] = f2b(a.y); r[2] = f2b(a.z); r[3] = f2b(a.w);
        r[4] = f2b(b.x); r[5] = f2b(b.y); r[6] = f2b(b.z); r[7] = f2b(b.w);
        return r;
    }
    return *(const bf16x8*)((const bf16*)p + off);
}
__device__ __forceinline__ float loadf(const void* p, size_t off, bool f32) {
    return f32 ? ((const float*)p)[off]
               : __bfloat162float(((const bf16*)p)[off]);
}

// ---------------------------------------------------------------------------
// Runtime dtype detection, one wave.
// bit0: float tensors are fp32 ; bit1: node_id_A int64 ; bit2: edges int64
// ---------------------------------------------------------------------------
__global__ void detect(const unsigned int* __restrict__ xA_bits,
                       const unsigned int* __restrict__ idA_bits,
                       const unsigned int* __restrict__ eAB_bits,
                       int* __restrict__ flags)
{
    int lane = threadIdx.x;
    int inr = 0;
#pragma unroll
    for (int j = 0; j < 4; j++) {
        unsigned e = (xA_bits[lane * 4 + j] >> 7) & 0xFF;
        inr += (e >= 100 && e <= 135) ? 1 : 0;
    }
#pragma unroll
    for (int s = 32; s > 0; s >>= 1) inr += __shfl_down(inr, s);
    unsigned long long idnz = __ballot(idA_bits[2 * lane + 1] != 0);
    unsigned long long enz  = __ballot(eAB_bits[2 * lane + 1] != 0);
    if (lane == 0) {
        int f32  = (inr < 128) ? 1 : 0;
        int id64 = (idnz == 0) ? 1 : 0;
        int e64  = (enz == 0) ? 1 : 0;
        flags[0] = f32 | (id64 << 1) | (e64 << 2);
    }
}

// ---------------------------------------------------------------------------
// Convert all weight/bias params to bf16 once.
// R10 post-mortem: the WlBA branch MUST use off = t - P_WLBA. A cleanup in
// R4 kept a buggy chain (off = t - P_BLBA -> size_t underflow -> OOB reads,
// absmax 1.49). Verified against the R0 baseline mapping element-by-element.
// ---------------------------------------------------------------------------
#define P_LINW  0
#define P_LINB  8192
#define P_WLAB  8320
#define P_BLAB  41088
#define P_WRAB  41344
#define P_WLBA  74112
#define P_BLBA  106880
#define P_WRBA  107136
#define P_TOTAL 139904

__global__ void convert_params(const void* __restrict__ linW, const void* __restrict__ linb,
                               const void* __restrict__ WlAB, const void* __restrict__ blAB,
                               const void* __restrict__ WrAB, const void* __restrict__ WlBA,
                               const void* __restrict__ blBA, const void* __restrict__ WrBA,
                               bf16* __restrict__ dst, const int* __restrict__ flags)
{
    bool f32 = flags[0] & 1;
    int t = blockIdx.x * blockDim.x + threadIdx.x;
    if (t >= P_TOTAL) return;
    const void* src; size_t off;
    if      (t < P_LINB) { src = linW; off = t - P_LINW; }
    else if (t < P_WLAB) { src = linb; off = t - P_LINB; }
    else if (t < P_BLAB) { src = WlAB; off = t - P_WLAB; }
    else if (t < P_WRAB) { src = blAB; off = t - P_BLAB; }
    else if (t < P_WLBA) { src = WrAB; off = t - P_WRAB; }
    else if (t < P_BLBA) { src = WlBA; off = t - P_WLBA; }
    else if (t < P_WRBA) { src = blBA; off = t - P_BLBA; }
    else                 { src = WrBA; off = t - P_WRBA; }
    dst[t] = __float2bfloat16(loadf(src, off, f32));
}

// ---------------------------------------------------------------------------
// Build COLUMN-MAJOR padded adjacency: adj[pos*NSLICE + dst] = src.
// XCD-OWNED dst partitioning: chunk c = blockIdx%8 rides the round-robin
// block->XCD mapping, so dst range [c*PWIN,(c+1)*PWIN) is written by ONE
// XCD's L2 only. R3 counters showed time-windowed passes alone leave
// WRITE_SIZE at 84.5 MB (~6.5x ideal): all 8 XCD L2s dirtied the same
// lines, each evicting its own partial copy. Single-writer-XCD makes each
// adjacency line fill while resident and evict dirty once.
// Edge list is re-streamed by each XCD (L3-resident).
// ---------------------------------------------------------------------------
__global__ void build_adj(const int* __restrict__ eAB, const int* __restrict__ eBA,
                          int* __restrict__ adjAB, int* __restrict__ cntB,
                          int* __restrict__ adjBA, int* __restrict__ cntA,
                          int cap, const int* __restrict__ flags)
{
    int st = (flags[0] & 4) ? 2 : 1;   // int64 edges: read low word (LE)
    int xcd   = blockIdx.x & (NXCD - 1);   // dst-chunk == XCD proxy
    int chunk = blockIdx.x >> 3;           // edge window
    int lo = xcd * PWIN;
    int hi = lo + PWIN;
    int e = chunk * blockDim.x + threadIdx.x;
    if (e < NE) {
        int dst = eAB[(size_t)(NE + e) * st];
        if (dst >= lo && dst < hi) {
            int src = eAB[(size_t)e * st];
            int pos = atomicAdd(&cntB[dst], 1);
            if (pos < cap) adjAB[(size_t)pos * NSLICE + dst] = src;
        }
    } else {
        int e2 = e - NE;
        if (e2 < NE) {
            int dst = eBA[(size_t)(NE + e2) * st];
            if (dst >= lo && dst < hi) {
                int src = eBA[(size_t)e2 * st];
                int pos = atomicAdd(&cntA[dst], 1);
                if (pos < cap) adjBA[(size_t)pos * NSLICE + dst] = src;
            }
        }
    }
}

// ---------------------------------------------------------------------------
// xA = x_A @ linA_W^T + linA_b + emb_A[idA]   (MFMA K=64; W/b pre-bf16)
// ---------------------------------------------------------------------------
__global__ __launch_bounds__(256) void fuse_input(
    const void* __restrict__ xin, const int* __restrict__ idA,
    const void* __restrict__ embA, const bf16* __restrict__ Wb,
    const bf16* __restrict__ bb, bf16* __restrict__ out,
    const int* __restrict__ flags)
{
    int fl = flags[0];
    bool f32 = fl & 1;
    int idst = (fl & 2) ? 2 : 1;
    int lane = threadIdx.x & 63;
    int wid  = threadIdx.x >> 6;
    int m0   = (blockIdx.x * 4 + wid) * 16;
    if (m0 >= N_A_NODES) return;
    int r = lane & 15, q = lane >> 4;

    floatx4 acc[8] = {};
#pragma unroll
    for (int s = 0; s < 2; s++) {
        bf16x8 a = load8(xin, (size_t)(m0 + r) * D_FEAT + s * 32 + q * 8, f32);
#pragma unroll
        for (int t = 0; t < 8; t++) {
            bf16x8 b = *(const bf16x8*)(Wb + (size_t)(t * 16 + r) * D_FEAT + s * 32 + q * 8);
            acc[t] = __builtin_amdgcn_mfma_f32_16x16x32_bf16(a, b, acc[t], 0, 0, 0);
        }
    }
#pragma unroll
    for (int t = 0; t < 8; t++) {
        int col = t * 16 + r;
        float bf = __bfloat162float(bb[col]);
#pragma unroll
        for (int rr = 0; rr < 4; rr++) {
            int row = m0 + q * 4 + rr;
            int id = idA[(size_t)row * idst];
            float v = acc[t][rr] + bf + loadf(embA, (size_t)id * HIDDEN + col, f32);
            out[(size_t)row * HIDDEN + col] = __float2bfloat16(v);
        }
    }
}

// ---------------------------------------------------------------------------
// xB = emb_B[idB]  (row gather, 4 elements/thread)
// ---------------------------------------------------------------------------
__global__ void copy_embB(const void* __restrict__ emb, const int* __restrict__ idB,
                          bf16* __restrict__ out, const int* __restrict__ flags)
{
    bool f32 = flags[0] & 1;
    int t = blockIdx.x * blockDim.x + threadIdx.x;
    int row = t >> 5;
    int g   = t & 31;
    if (row >= N_B_NODES) return;
    size_t s = (size_t)idB[row] * HIDDEN + g * 4;
    size_t d = (size_t)row * HIDDEN + g * 4;
    if (f32) {
        float4 v = *(const float4*)((const float*)emb + s);
        union { bf16 h[4]; uint2 u; } pk;
        pk.h[0] = __float2bfloat16(v.x); pk.h[1] = __float2bfloat16(v.y);
        pk.h[2] = __float2bfloat16(v.z); pk.h[3] = __float2bfloat16(v.w);
        *(uint2*)(out + d) = pk.u;
    } else {
        *(uint2*)(out + d) = *(const uint2*)((const bf16*)emb + s);
    }
}

// ---------------------------------------------------------------------------
// segment mean: one wave per dst node, fp32 accumulate; column-major adj.
// Quarter-wave gather (R3-verified: removed aggregate from top-5):
// 16 lanes x bf16x8 cover one 256-B feat row; one vmem instr = 4 edges;
// unroll x2 = 8 edges in flight. adj vector-loaded once + shfl broadcast.
// ---------------------------------------------------------------------------
__device__ __forceinline__ void accum8(float* acc, bf16x8 v) {
    union { bf16x8 v8; __hip_bfloat162 h2[4]; } u;
    u.v8 = v;
#pragma unroll
    for (int j = 0; j < 4; j++) {
        float2 f = __bfloat1622float2(u.h2[j]);
        acc[2 * j]     += f.x;
        acc[2 * j + 1] += f.y;
    }
}

__global__ __launch_bounds__(256) void aggregate(
    const bf16* __restrict__ feat, const int* __restrict__ adj,
    const int* __restrict__ cnt, void* __restrict__ outbase, size_t out_eoff,
    int m_mode, int Ndst, int cap, const int* __restrict__ flags)
{
    bool f32sel = m_mode ? (flags[0] & 1) : false;
    int wid  = (blockIdx.x * blockDim.x + threadIdx.x) >> 6;
    int lane = threadIdx.x & 63;
    if (wid >= Ndst) return;

    int c = cnt[wid];
    int n = c < cap ? c : cap;

    // one coalesced vector load replaces n serial lane-uniform loads
    int myadj = (lane < n) ? adj[(size_t)lane * NSLICE + wid] : 0;

    int q  = lane >> 4;        // quarter-wave: which edge of the group of 4
    int cl = lane & 15;        // column block: 8 bf16 per lane

    float acc[8] = {};
    int e = 0;
    for (; e + 8 <= n; e += 8) {
        int s0 = __shfl(myadj, e + q);
        int s1 = __shfl(myadj, e + 4 + q);
        bf16x8 v0 = *(const bf16x8*)(feat + (size_t)s0 * HIDDEN + cl * 8);
        bf16x8 v1 = *(const bf16x8*)(feat + (size_t)s1 * HIDDEN + cl * 8);
        accum8(acc, v0);
        accum8(acc, v1);
    }
    for (; e < n; e += 4) {
        int idx = e + q;
        int s = __shfl(myadj, idx < n ? idx : 0);
        bf16x8 v = *(const bf16x8*)(feat + (size_t)s * HIDDEN + cl * 8);
        if (idx < n) accum8(acc, v);
    }

    // reduce across the 4 quarter-waves (same cl, different q)
#pragma unroll
    for (int j = 0; j < 8; j++) {
        acc[j] += __shfl_xor(acc[j], 16);
        acc[j] += __shfl_xor(acc[j], 32);
    }

    float scale = 1.0f / (float)(c > 1 ? c : 1);
    if (q == 0) {
        size_t rowbase = out_eoff + (size_t)wid * HIDDEN + cl * 8;
        if (f32sel) {
            float* op = (float*)outbase + rowbase;
            *(float4*)op       = make_float4(acc[0] * scale, acc[1] * scale,
                                             acc[2] * scale, acc[3] * scale);
            *(float4*)(op + 4) = make_float4(acc[4] * scale, acc[5] * scale,
                                             acc[6] * scale, acc[7] * scale);
        } else {
            union { bf16 h[8]; uint4 u; } pk;
#pragma unroll
            for (int j = 0; j < 8; j++) pk.h[j] = __float2bfloat16(acc[j] * scale);
            *(uint4*)((bf16*)outbase + rowbase) = pk.u;
        }
    }
}

// ---------------------------------------------------------------------------
// out = relu(A1 @ W1^T + bias + A2 @ W2^T)   (fused K=256 MFMA GEMM)
// A1: bf16 (a1_mode 0) or external dtype (a1_mode 1).  A2/W/b: bf16.
// out: internal bf16 (out_ext 0) or external dtype (out_ext 1).
// In-place safe (out aliasing A1/A2): each wave reads only rows it writes.
// ---------------------------------------------------------------------------
__global__ __launch_bounds__(256) void gemm_dual(
    const void* __restrict__ A1base, size_t a1_eoff, int a1_mode,
    const bf16* __restrict__ A2,
    const bf16* __restrict__ W1, const bf16* __restrict__ W2,
    const bf16* __restrict__ bias,
    void* __restrict__ outbase, size_t out_eoff, int out_ext,
    int N, const int* __restrict__ flags)
{
    bool extf32 = flags[0] & 1;
    bool a1f32  = a1_mode && extf32;
    bool outf   = out_ext && extf32;
    int lane = threadIdx.x & 63;
    int wid  = threadIdx.x >> 6;
    int m0   = (blockIdx.x * 4 + wid) * 16;
    if (m0 >= N) return;
    int r = lane & 15, q = lane >> 4;

    floatx4 acc[8] = {};
#pragma unroll
    for (int s = 0; s < 4; s++) {
        bf16x8 a = load8(A1base, a1_eoff + (size_t)(m0 + r) * HIDDEN + s * 32 + q * 8, a1f32);
#pragma unroll
        for (int t = 0; t < 8; t++) {
            bf16x8 b = *(const bf16x8*)(W1 + (size_t)(t * 16 + r) * HIDDEN + s * 32 + q * 8);
            acc[t] = __builtin_amdgcn_mfma_f32_16x16x32_bf16(a, b, acc[t], 0, 0, 0);
        }
    }
#pragma unroll
    for (int s = 0; s < 4; s++) {
        bf16x8 a = *(const bf16x8*)(A2 + (size_t)(m0 + r) * HIDDEN + s * 32 + q * 8);
#pragma unroll
        for (int t = 0; t < 8; t++) {
            bf16x8 b = *(const bf16x8*)(W2 + (size_t)(t * 16 + r) * HIDDEN + s * 32 + q * 8);
            acc[t] = __builtin_amdgcn_mfma_f32_16x16x32_bf16(a, b, acc[t], 0, 0, 0);
        }
    }
#pragma unroll
    for (int t = 0; t < 8; t++) {
        int col = t * 16 + r;
        float bf = __bfloat162float(bias[col]);
#pragma unroll
        for (int rr = 0; rr < 4; rr++) {
            float v = acc[t][rr] + bf;
            v = v > 0.f ? v : 0.f;
            size_t eo = out_eoff + (size_t)(m0 + q * 4 + rr) * HIDDEN + col;
            if (outf) ((float*)outbase)[eo] = v;
            else      ((bf16*)outbase)[eo] = __float2bfloat16(v);
        }
    }
}

// ---------------------------------------------------------------------------
extern "C" void kernel_launch(void* const* d_in, const int* in_sizes, int n_in,
                              void* d_out, int out_size, void* d_ws, size_t ws_size,
                              hipStream_t stream)
{
    const void* x_A  = d_in[0];
    const int*  idA  = (const int*)d_in[1];
    const int*  idB  = (const int*)d_in[2];
    const int*  eAB  = (const int*)d_in[3];
    const int*  eBA  = (const int*)d_in[4];
    const void* embA = d_in[5];
    const void* embB = d_in[6];

    // ---- workspace layout ----
    char* ws = (char*)d_ws;
    int*  cntB  = (int*)(ws + 0);           // 400000 B
    int*  cntA  = (int*)(ws + 400000);      // 400000 B
    int*  flags = (int*)(ws + 800000);      // 64 B
    bf16* pblk  = (bf16*)(ws + 800064);     // 279808 B of bf16 params
    const size_t XA_OFF = 1080000;
    const size_t XB_OFF = XA_OFF + 25600000;   // 26680000
    const size_t M_OFF  = XB_OFF + 25600000;   // 52280000
    bf16* xA = (bf16*)(ws + XA_OFF);
    bf16* xB = (bf16*)(ws + XB_OFF);

    // mAB/mBA: prefer bf16 in ws; fall back to external-dtype scratch in d_out
    // if ws is too small to also hold a decent adjacency.
    const size_t ADJ_M = M_OFF + 51200000;     // 103480000
    long long cap_m = ((long long)ws_size - (long long)ADJ_M) / 800000;
    int m_in_ws = (cap_m >= 16) ? 1 : 0;
    size_t adj_off = m_in_ws ? ADJ_M : M_OFF;
    long long capl = ((long long)ws_size - (long long)adj_off) / 800000;
    int cap = (int)capl;
    if (cap > CAP_MAX) cap = CAP_MAX;
    if (cap < 1) cap = 1;
    int* adjAB = (int*)(ws + adj_off);
    int* adjBA = (int*)(ws + adj_off + (size_t)cap * 400000);

    const size_t OUTB_EOFF = (size_t)N_A_NODES * HIDDEN;
    void*  mAB_base = m_in_ws ? (void*)(ws + M_OFF)            : d_out;
    void*  mBA_base = m_in_ws ? (void*)(ws + M_OFF + 25600000) : d_out;
    size_t mAB_eoff = m_in_ws ? 0 : OUTB_EOFF;
    size_t mBA_eoff = 0;
    int    m_mode   = m_in_ws ? 0 : 1;

    // bf16 param slices
    bf16* linWb = pblk + P_LINW;
    bf16* linbb = pblk + P_LINB;
    bf16* WlABb = pblk + P_WLAB;
    bf16* blABb = pblk + P_BLAB;
    bf16* WrABb = pblk + P_WRAB;
    bf16* WlBAb = pblk + P_WLBA;
    bf16* blBAb = pblk + P_BLBA;
    bf16* WrBAb = pblk + P_WRBA;

    (void)hipMemsetAsync(cntB, 0, 800000, stream);  // zeros cntB + cntA

    detect<<<1, 64, 0, stream>>>((const unsigned int*)x_A, (const unsigned int*)idA,
                                 (const unsigned int*)eAB, flags);
    convert_params<<<(P_TOTAL + 255) / 256, 256, 0, stream>>>(
        d_in[7], d_in[8], d_in[9], d_in[10], d_in[11], d_in[12], d_in[13], d_in[14],
        pblk, flags);
    build_adj<<<NXCD * BPP, 256, 0, stream>>>(eAB, eBA, adjAB, cntB,
                                              adjBA, cntA, cap, flags);
    fuse_input<<<(N_A_NODES + 63) / 64, 256, 0, stream>>>(x_A, idA, embA, linWb,
                                                          linbb, xA, flags);
    copy_embB<<<(N_B_NODES * 32 + 255) / 256, 256, 0, stream>>>(embB, idB, xB, flags);

    for (int l = 0; l < 2; l++) {
        bf16* wl_ab = WlABb + (size_t)l * HIDDEN * HIDDEN;
        bf16* wr_ab = WrABb + (size_t)l * HIDDEN * HIDDEN;
        bf16* wl_ba = WlBAb + (size_t)l * HIDDEN * HIDDEN;
        bf16* wr_ba = WrBAb + (size_t)l * HIDDEN * HIDDEN;
        bf16* b_ab  = blABb + (size_t)l * HIDDEN;
        bf16* b_ba  = blBAb + (size_t)l * HIDDEN;

        aggregate<<<(N_B_NODES + 3) / 4, 256, 0, stream>>>(
            xA, adjAB, cntB, mAB_base, mAB_eoff, m_mode, N_B_NODES, cap, flags);
        aggregate<<<(N_A_NODES + 3) / 4, 256, 0, stream>>>(
            xB, adjBA, cntA, mBA_base, mBA_eoff, m_mode, N_A_NODES, cap, flags);

        if (l == 0) {
            gemm_dual<<<(N_B_NODES + 63) / 64, 256, 0, stream>>>(
                mAB_base, mAB_eoff, m_mode, xB, wl_ab, wr_ab, b_ab,
                xB, 0, 0, N_B_NODES, flags);
            gemm_dual<<<(N_A_NODES + 63) / 64, 256, 0, stream>>>(
                mBA_base, mBA_eoff, m_mode, xA, wl_ba, wr_ba, b_ba,
                xA, 0, 0, N_A_NODES, flags);
        } else {
            gemm_dual<<<(N_B_NODES + 63) / 64, 256, 0, stream>>>(
                mAB_base, mAB_eoff, m_mode, xB, wl_ab, wr_ab, b_ab,
                d_out, OUTB_EOFF, 1, N_B_NODES, flags);
            gemm_dual<<<(N_A_NODES + 63) / 64, 256, 0, stream>>>(
                mBA_base, mBA_eoff, m_mode, xA, wl_ba, wr_ba, b_ba,
                d_out, 0, 1, N_A_NODES, flags);
        }
    }
}